// Round 12
// baseline (5241.606 us; speedup 1.0000x reference)
//
#include <hip/hip_runtime.h>
#include <math.h>

// ToxicityLSTM: 2-layer LSTM (B=64, T=1024, H=256, gates i,j,f,o, forget
// bias 1.0) + linear head (256->6) + sigmoid + threshold.
//
// Round 12: EPOCH-ENCODED h ("sentinel in data") + free-running blocks.
// No grid barrier, no data flags. Producers store henc = h + e(s), with
// e(s) = ((s&31)+1)*4 in [4,128]; |h|<=1 makes the e+-1 ranges disjoint
// across the 32-epoch cycle (buffers are 16 deep -> same-slot stale value
// differs by 64). Consumers poll their own gather loads until every
// component is in range, then decode v - e. This collapses the old
// finish->store->flagRT->poll->barrier->gather chain to finish->store->
// (data visible)->gather: one LLC trip instead of three, and each layer
// waits only on its own 32 producers.
//   - Geometry (R3/R9-proven): 256 blocks x 512 thr, 1 block/CU. Blocks
//     0..127 = L1, 128..255 = L2; bgrp = 16 batches; block = 8u x 16b.
//     W slice [4g][32k] in VGPRs; skewed hstage (0 conflicts); 16-way
//     k-combine via padded partials (double-buffered); finisher tid<128.
//   - Per step s (both layers run s = 0..1023, L2 self-paced by polls):
//     even waves: L1 stage x(s) (plain) / L2 poll-gather h1(s) (slack:
//     L1 runs ahead, passes instantly); odd waves: poll-gather own-layer
//     recurrent half (h1(s-1) / h2(s-1)) -- the tight dep. Scout (4B/lane)
//     then bulk (4x16B/lane) polling limits retry fabric traffic.
//   - Anti-deps: 16-deep buffers; within-layer skew <=1 (data-coupled) ->
//     auto-safe. Cross-layer: L2 publishes progress flag; L1 waits
//     flag >= s-15 before overwriting h1 slot s&15 (kills h1(s-16), whose
//     only reader is L2@(s-16)). ~14 steps of slack -> off critical path.
//   - Startup: slot 15 of h1/h2 pre-filled with 128.0f = encode of
//     h(-1)=0 under e(-1)=128. Memset + refill every launch (replay-safe).
//   - Head decodes h2(1023): slot 1023&15=15, e(1023)=128.

#define BB 64
#define TT 1024
#define HH 256
#define NTHREADS 512
#define DEPTH 16
#define FLAG_BYTES 4096                  // 4 bgrp x 32 L2-progress flags
#define HBUF_FLOATS (BB * HH)            // 16384 floats per slot
#define WT_FLOATS (256 * 4 * 512)        // 524288 floats per layer
#define WS_NEEDED (FLAG_BYTES + (size_t)2 * DEPTH * HBUF_FLOATS * 4 + (size_t)2 * WT_FLOATS * 4)
#define HROW 576                         // skewed panel row stride (floats)

typedef float f32x4 __attribute__((ext_vector_type(4)));

__device__ __forceinline__ float emap(int s) {   // epoch sentinel offset
  return (float)(((s & 31) + 1) * 4);
}
__device__ __forceinline__ void coh_store(float* p, float v) {
  __hip_atomic_store(p, v, __ATOMIC_RELAXED, __HIP_MEMORY_SCOPE_AGENT);
}
__device__ __forceinline__ void coh_store_i(int* p, int v) {
  __hip_atomic_store(p, v, __ATOMIC_RELAXED, __HIP_MEMORY_SCOPE_AGENT);
}
__device__ __forceinline__ int ld_flag(const int* p) {
  int v;
  asm volatile("global_load_dword %0, %1, off sc0 sc1\n\ts_waitcnt vmcnt(0)"
               : "=v"(v) : "v"(p) : "memory");
  return v;
}
__device__ __forceinline__ float ld_scout(const float* p) {
  float v;
  asm volatile("global_load_dword %0, %1, off sc0 sc1\n\ts_waitcnt vmcnt(0)"
               : "=v"(v) : "v"(p) : "memory");
  return v;
}
// 4 device-coherent float4 loads in flight, one vmcnt drain (BLOCKING).
__device__ __forceinline__ void coh_load4(
    const float* p0, const float* p1, const float* p2, const float* p3,
    f32x4& a0, f32x4& a1, f32x4& a2, f32x4& a3) {
  asm volatile(
      "global_load_dwordx4 %0, %4, off sc0 sc1\n\t"
      "global_load_dwordx4 %1, %5, off sc0 sc1\n\t"
      "global_load_dwordx4 %2, %6, off sc0 sc1\n\t"
      "global_load_dwordx4 %3, %7, off sc0 sc1\n\t"
      "s_waitcnt vmcnt(0)"
      : "=&v"(a0), "=&v"(a1), "=&v"(a2), "=&v"(a3)
      : "v"(p0), "v"(p1), "v"(p2), "v"(p3)
      : "memory");
}
__device__ __forceinline__ bool ok4(f32x4 v, float e) {
  const float m0 = fmaxf(fabsf(v[0] - e), fabsf(v[1] - e));
  const float m1 = fmaxf(fabsf(v[2] - e), fabsf(v[3] - e));
  return fmaxf(m0, m1) <= 1.0f;
}
// Poll-gather 4 rows (stride rs) x 16B at p0, expected epoch e; decode.
__device__ __forceinline__ void gather_poll(
    const float* p0, int rs, float e,
    f32x4& a0, f32x4& a1, f32x4& a2, f32x4& a3) {
  for (;;) {                                   // scout: 4B/lane per retry
    const float v = ld_scout(p0);
    if (__all(fabsf(v - e) <= 1.0f)) break;
    __builtin_amdgcn_s_sleep(2);
  }
  for (;;) {                                   // bulk: usually 1 iteration
    coh_load4(p0, p0 + rs, p0 + 2 * rs, p0 + 3 * rs, a0, a1, a2, a3);
    const bool ok = ok4(a0, e) && ok4(a1, e) && ok4(a2, e) && ok4(a3, e);
    if (__all(ok)) break;
    __builtin_amdgcn_s_sleep(2);
  }
  a0 -= e; a1 -= e; a2 -= e; a3 -= e;          // decode
}

// Fast sigmoid/tanh on v_exp_f32 + v_rcp_f32 (R9-validated, absmax 0).
__device__ __forceinline__ float fsig(float x) {
  const float e = __builtin_amdgcn_exp2f(x * -1.442695040888963f);
  return __builtin_amdgcn_rcpf(1.0f + e);
}
__device__ __forceinline__ float ftanh(float x) {
  const float e = __builtin_amdgcn_exp2f(x * 2.885390081777927f);
  return 1.0f - 2.0f * __builtin_amdgcn_rcpf(e + 1.0f);
}

// One-time weight transpose: src [512 k][4 g * 256 u] -> dst [256 u][4 g][512 k]
__global__ void transpose_w(const float* __restrict__ src, float* __restrict__ dst) {
  __shared__ float t[64][65];
  const int g  = blockIdx.x;
  const int kt = blockIdx.y;
  const int ut = blockIdx.z;
  const int tx = threadIdx.x & 63;
  const int ty = threadIdx.x >> 6;
  #pragma unroll
  for (int r = ty; r < 64; r += 4)
    t[r][tx] = src[(size_t)(kt * 64 + r) * 1024 + g * 256 + ut * 64 + tx];
  __syncthreads();
  #pragma unroll
  for (int r = ty; r < 64; r += 4)
    dst[((size_t)(ut * 64 + r) * 4 + g) * 512 + kt * 64 + tx] = t[tx][r];
}

// Pre-fill the t=-1 sentinel slots: encode of h=0 under e(-1)=128.
__global__ void init_sentinels(float* __restrict__ h1b, float* __restrict__ h2b) {
  const int i = blockIdx.x * blockDim.x + threadIdx.x;
  if (i < HBUF_FLOATS) {
    h1b[(size_t)15 * HBUF_FLOATS + i] = 128.0f;
    h2b[(size_t)15 * HBUF_FLOATS + i] = 128.0f;
  }
}

__global__ __launch_bounds__(NTHREADS, 2) void lstm2_persistent(
    const float* __restrict__ x,
    const float* __restrict__ b0, const float* __restrict__ b1,
    const float* __restrict__ wt0, const float* __restrict__ wt1,
    float* __restrict__ h1buf, float* __restrict__ h2buf,
    int* __restrict__ l2f)
{
  __shared__ float hstage[16 * HROW];     // 36864 B operand panel (skewed)
  __shared__ f32x4 part[2][128 * 17];     // 2 x 34816 B k-partials (dbuf)

  const int blk   = blockIdx.x;
  const int taskB = blk >= 128;                  // layer2 blocks
  const int tblk  = taskB ? blk - 128 : blk;
  const int bgrp  = tblk >> 5;                   // 4 groups of 16 b
  const int ublk  = tblk & 31;                   // 32 groups of 8 u

  const int tid  = threadIdx.x;
  const int lane = tid & 63;
  const int wv   = tid >> 6;
  const int ul   = tid & 7;
  const int kq   = (tid >> 3) & 15;              // even waves 0-7, odd 8-15
  const int bt   = tid >> 7;
  const bool odd = wv & 1;                       // high-half (k 256..511)
  const int r0S  = bt * 4;                       // my 4 panel rows
  const int cS   = lane + (odd ? 64 : 0);        // staging f4-col
  const int dposS = cS * 4 + (cS >> 3) * 4;      // skewed in-row position

  const float* WT   = taskB ? wt1 : wt0;
  const float* bias = taskB ? b1 : b0;

  // ---- loop-invariant weight slice into registers: [4 g][32 k] ----
  f32x4 w[4][8];
  {
    const float* wb = WT + (size_t)(ublk * 8 + ul) * 2048 + kq * 32;
    #pragma unroll
    for (int g = 0; g < 4; ++g)
      #pragma unroll
      for (int cc = 0; cc < 8; ++cc)
        w[g][cc] = *(const f32x4*)(wb + g * 512 + cc * 4);
  }

  // ---- finisher state (threads 0..127 own one (b,u)) ----
  float bi = 0.f, bj = 0.f, bfv = 0.f, bo = 0.f;
  if (tid < 128) {
    const int u = ublk * 8 + (tid & 7);
    bi  = bias[u];
    bj  = bias[256 + u];
    bfv = bias[512 + u];
    bo  = bias[768 + u];
  }
  float cst = 0.f;

  const size_t browoff = (size_t)(bgrp * 16 + r0S) * HH + lane * 4;

  for (int s = 0; s < TT; ++s) {
    const float ecur  = emap(s);
    const float eprev = emap(s - 1);
    const int   scur  = s & 15;
    const int   sprev = (s + 15) & 15;

    // ======== stage panel (wave-private rows x cols, no pre-gemv sync) ====
    f32x4 v0, v1, v2, v3;
    if (!odd) {
      if (!taskB) {
        // L1 low = x(s): plain cacheable loads
        const float* bx = x + ((size_t)(bgrp * 16 + r0S) * TT + s) * HH + lane * 4;
        const size_t rstep = (size_t)TT * HH;
        v0 = *(const f32x4*)(bx);
        v1 = *(const f32x4*)(bx + rstep);
        v2 = *(const f32x4*)(bx + 2 * rstep);
        v3 = *(const f32x4*)(bx + 3 * rstep);
      } else {
        // L2 low = h1(s): slack dep (L1 runs ahead) -> usually instant
        const float* p0 = h1buf + (size_t)scur * HBUF_FLOATS + browoff;
        gather_poll(p0, HH, ecur, v0, v1, v2, v3);
      }
    } else {
      // odd waves: tight own-layer recurrent half, h?(s-1)
      const float* p0 = (taskB ? h2buf : h1buf) + (size_t)sprev * HBUF_FLOATS + browoff;
      gather_poll(p0, HH, eprev, v0, v1, v2, v3);
    }
    *(f32x4*)&hstage[(r0S + 0) * HROW + dposS] = v0;
    *(f32x4*)&hstage[(r0S + 1) * HROW + dposS] = v1;
    *(f32x4*)&hstage[(r0S + 2) * HROW + dposS] = v2;
    *(f32x4*)&hstage[(r0S + 3) * HROW + dposS] = v3;
    // (no sync: every wave reads only the rows x cols it staged itself)

    // ======== gemv: 4 b x 4 g accumulators over own 32-k slice ========
    float acc[4][4];
    #pragma unroll
    for (int b4 = 0; b4 < 4; ++b4)
      #pragma unroll
      for (int g = 0; g < 4; ++g) acc[b4][g] = 0.f;

    const int kbase = kq * 36;
    #pragma unroll
    for (int b4 = 0; b4 < 4; ++b4) {
      const float* hp = &hstage[(r0S + b4) * HROW + kbase];
      #pragma unroll
      for (int cc = 0; cc < 8; ++cc) {
        const f32x4 h4 = *(const f32x4*)(hp + cc * 4);
        #pragma unroll
        for (int g = 0; g < 4; ++g) {
          acc[b4][g] = fmaf(h4[0], w[g][cc][0], acc[b4][g]);
          acc[b4][g] = fmaf(h4[1], w[g][cc][1], acc[b4][g]);
          acc[b4][g] = fmaf(h4[2], w[g][cc][2], acc[b4][g]);
          acc[b4][g] = fmaf(h4[3], w[g][cc][3], acc[b4][g]);
        }
      }
    }

    // ---- 16-way k-combine via padded LDS partials (double-buffered) ----
    #pragma unroll
    for (int b4 = 0; b4 < 4; ++b4) {
      f32x4 p = { acc[b4][0], acc[b4][1], acc[b4][2], acc[b4][3] };
      part[s & 1][((r0S + b4) * 8 + ul) * 17 + kq] = p;
    }
    __syncthreads();   // the ONLY block sync per step

    // ======== finish (waves 0-1): gates, epoch-encoded h store ========
    if (tid < 128) {
      float gi = bi, gj = bj, gf = bfv, go = bo;
      #pragma unroll
      for (int q = 0; q < 16; ++q) {
        const f32x4 p = part[s & 1][tid * 17 + q];
        gi += p[0]; gj += p[1]; gf += p[2]; go += p[3];
      }
      const float ig = fsig(gi);
      const float jt = ftanh(gj);
      const float fg = fsig(gf + 1.0f);
      const float og = fsig(go);
      cst = fg * cst + ig * jt;
      const float hn = og * ftanh(cst);

      // L1 back-pressure: before overwriting h1(s-16) (slot scur), its only
      // reader L2@(s-16) must be done: L2 progress flag >= s-15.
      if (!taskB && s >= DEPTH) {
        const int thr = s - (DEPTH - 1);
        const int* fp = l2f + bgrp * 32 + (lane & 31);
        for (;;) {
          const int f = (lane < 32) ? ld_flag(fp) : thr;
          if (__all(f >= thr)) break;
          __builtin_amdgcn_s_sleep(2);
        }
      }

      float* hb = (taskB ? h2buf : h1buf) + (size_t)scur * HBUF_FLOATS;
      coh_store(hb + (size_t)(bgrp * 16 + (tid >> 3)) * HH + ublk * 8 + (tid & 7),
                hn + ecur);   // epoch-encoded: the store IS the signal

      // L2 publishes progress (certifies its h1(s) read is complete).
      if (taskB && tid == 0) coh_store_i(l2f + bgrp * 32 + ublk, s + 1);
    }
  }
}

// Head: logits = decode(h2_last) @ w_out + b_out; sigmoid; threshold.
__global__ void head_kernel(const float* __restrict__ h2last,
                            const float* __restrict__ w_out,
                            const float* __restrict__ b_out,
                            float* __restrict__ out)
{
  int tid = threadIdx.x;
  if (tid >= 384) return;
  int bb = tid / 6, cc = tid % 6;
  float acc = b_out[cc];
  const float* hr = h2last + bb * HH;
  #pragma unroll 4
  for (int uu = 0; uu < HH; ++uu)
    acc = fmaf(hr[uu] - 128.0f, w_out[uu * 6 + cc], acc);  // decode e(1023)=128
  out[tid] = acc;                            // logits
  float sg = 1.f / (1.f + expf(-acc));
  out[384 + tid] = sg;                       // sigmoid output
  out[768 + tid] = (sg > 0.5f) ? 1.f : 0.f;  // prediction
}

extern "C" void kernel_launch(void* const* d_in, const int* in_sizes, int n_in,
                              void* d_out, int out_size, void* d_ws, size_t ws_size,
                              hipStream_t stream) {
  const float* x     = (const float*)d_in[0];
  const float* k0    = (const float*)d_in[1];
  const float* b0    = (const float*)d_in[2];
  const float* k1    = (const float*)d_in[3];
  const float* b1    = (const float*)d_in[4];
  const float* w_out = (const float*)d_in[5];
  const float* b_out = (const float*)d_in[6];
  float* out = (float*)d_out;

  if (ws_size < WS_NEEDED) return;  // visible failure if ws too small

  int*   l2f = (int*)d_ws;
  float* h1b = (float*)((char*)d_ws + FLAG_BYTES);   // 16 slots
  float* h2b = h1b + (size_t)DEPTH * HBUF_FLOATS;    // 16 slots
  float* wt0 = h2b + (size_t)DEPTH * HBUF_FLOATS;
  float* wt1 = wt0 + WT_FLOATS;

  // Zero flags + ALL h slots every launch (below-range => polls never match
  // stale data), then write the t=-1 sentinels. Graph-replay deterministic.
  hipMemsetAsync(d_ws, 0,
                 FLAG_BYTES + (size_t)2 * DEPTH * HBUF_FLOATS * 4, stream);
  init_sentinels<<<64, 256, 0, stream>>>(h1b, h2b);

  transpose_w<<<dim3(4, 8, 4), 256, 0, stream>>>(k0, wt0);
  transpose_w<<<dim3(4, 8, 4), 256, 0, stream>>>(k1, wt1);

  lstm2_persistent<<<256, NTHREADS, 0, stream>>>(x, b0, b1, wt0, wt1,
                                                 h1b, h2b, l2f);

  // h2(1023) lives in slot 1023 & 15 = 15 (epoch-encoded, e=128)
  head_kernel<<<1, 384, 0, stream>>>(h2b + (size_t)15 * HBUF_FLOATS,
                                     w_out, b_out, out);
}